// Round 1
// baseline (395.764 us; speedup 1.0000x reference)
//
#include <hip/hip_runtime.h>

// MLLoss: per-row hinge-margin loss over [B,16] distances, label-selected,
// mean-reduced to a scalar. Memory-bound: 256 MB distances + 32 MB labels.
//
// Layout: 4 lanes per row ("quad"), each lane loads one float4 (16 B) so every
// vector load is perfectly coalesced (64 lanes x 16 B contiguous per wave).
// hinge_sum reduced inside the quad with 2 shfl_xor; lane0-of-quad applies the
// doctor/real label selection. Block partial sums -> 1 atomicAdd per block,
// pre-scaled by 1/B to keep the float32 accumulator well-conditioned.

#define BLOCKS  2048
#define THREADS 256

__global__ __launch_bounds__(THREADS) void mlloss_kernel(
    const float4* __restrict__ dist4,   // B*4 float4 (row-major, 16 floats/row)
    const int*    __restrict__ doctor,  // [B] 0=control 1=parkinson 2=unknown
    const int*    __restrict__ real,    // [B] 0=control 1=parkinson
    float* __restrict__ out,            // [1] pre-zeroed
    int B, float invB)
{
    const int g       = blockIdx.x * blockDim.x + threadIdx.x;
    const int lane4   = g & 3;                       // float4 index within row
    const int qstride = (gridDim.x * blockDim.x) >> 2;

    float acc = 0.0f;

    for (int q = (g >> 2); q < B; q += qstride) {
        float4 d = dist4[(size_t)q * 4 + lane4];

        float h0 = fmaxf(1.0f - d.x, 0.0f);
        float h1 = fmaxf(1.0f - d.y, 0.0f);
        float h2 = fmaxf(1.0f - d.z, 0.0f);
        float h3 = fmaxf(1.0f - d.w, 0.0f);
        float s  = (h0 + h1) + (h2 + h3);

        // hinge_sum across the 4 lanes of this quad
        s += __shfl_xor(s, 1);
        s += __shfl_xor(s, 2);

        if ((threadIdx.x & 3) == 0) {
            // this lane holds row elements 0..3: d.x=d[0], d.y=d[1]
            int doc = doctor[q];
            int re  = real[q];
            float loss;
            if (doc == 0)      loss = d.x + s - h0;   // control
            else if (doc == 1) loss = d.y + s - h1;   // parkinson
            else               loss = (re == 0) ? h1 : h0;  // unknown
            acc += loss;
        }
    }

    // wave (64-lane) reduction; only lane0-of-quad holds nonzero acc
    #pragma unroll
    for (int m = 32; m >= 1; m >>= 1)
        acc += __shfl_xor(acc, m);

    __shared__ float wsum[THREADS / 64];
    const int wid = threadIdx.x >> 6;
    if ((threadIdx.x & 63) == 0) wsum[wid] = acc;
    __syncthreads();

    if (threadIdx.x == 0) {
        float t = 0.0f;
        #pragma unroll
        for (int w = 0; w < THREADS / 64; ++w) t += wsum[w];
        atomicAdd(out, t * invB);   // pre-scaled: accumulator stays ~3.25
    }
}

extern "C" void kernel_launch(void* const* d_in, const int* in_sizes, int n_in,
                              void* d_out, int out_size, void* d_ws, size_t ws_size,
                              hipStream_t stream) {
    const float4* dist4  = (const float4*)d_in[0];
    const int*    doctor = (const int*)d_in[1];
    const int*    real_l = (const int*)d_in[2];
    float*        out    = (float*)d_out;

    const int B = in_sizes[1];          // doctor_labels element count

    // d_out is re-poisoned to 0xAA before every replay -> zero it on-stream
    hipMemsetAsync(d_out, 0, sizeof(float) * (out_size > 0 ? out_size : 1), stream);

    mlloss_kernel<<<BLOCKS, THREADS, 0, stream>>>(
        dist4, doctor, real_l, out, B, 1.0f / (float)B);
}

// Round 3
// 357.955 us; speedup vs baseline: 1.1056x; 1.1056x over previous
//
#include <hip/hip_runtime.h>

// MLLoss: per-row hinge-margin loss over [B,16] fp32 distances, label-selected,
// mean-reduced to a scalar. Memory-bound: 256 MB distances + 32 MB labels.
//
// R3: same as R2 but with clang ext_vector float4 (HIP's float4 is a struct,
// which __builtin_nontemporal_load rejects; a native vector type is accepted
// and still emits one global_load_dwordx4 with the nt bit).
//
// Layout: 4 lanes per row ("quad"), each lane loads one 16 B vector so every
// load is perfectly coalesced (64 lanes x 16 B contiguous per wave).
// hinge_sum reduced inside the quad with 2 shfl_xor. All 4 quad lanes load the
// row's labels (same address -> HW broadcast) so control flow is uniform and
// #pragma unroll 4 gives 4 independent global-load chains per thread.
// Phase 1 writes one pre-scaled partial per block to d_ws; phase 2 (1 block)
// reduces 4096 partials and stores the scalar -> no memset, no atomics.

typedef float vfloat4 __attribute__((ext_vector_type(4)));

#define BLOCKS  4096
#define THREADS 256

__global__ __launch_bounds__(THREADS) void mlloss_partial(
    const vfloat4* __restrict__ dist4,  // B*4 vfloat4 (16 floats/row)
    const int*     __restrict__ doctor, // [B] 0=control 1=parkinson 2=unknown
    const int*     __restrict__ real,   // [B] 0=control 1=parkinson
    float* __restrict__ partials,       // [gridDim.x]
    int B, float invB)
{
    const int g       = blockIdx.x * blockDim.x + threadIdx.x;
    const int lane4   = threadIdx.x & 3;             // vector index within row
    const int qstride = (gridDim.x * blockDim.x) >> 2;

    float acc = 0.0f;

    #pragma unroll 4
    for (int q = (g >> 2); q < B; q += qstride) {
        vfloat4 d = __builtin_nontemporal_load(&dist4[(size_t)q * 4 + lane4]);
        int doc   = __builtin_nontemporal_load(&doctor[q]);  // same addr for
        int re    = __builtin_nontemporal_load(&real[q]);    // all 4 quad lanes

        float h0 = fmaxf(1.0f - d.x, 0.0f);
        float h1 = fmaxf(1.0f - d.y, 0.0f);
        float h2 = fmaxf(1.0f - d.z, 0.0f);
        float h3 = fmaxf(1.0f - d.w, 0.0f);
        float s  = (h0 + h1) + (h2 + h3);

        // hinge_sum across the 4 lanes of this quad
        s += __shfl_xor(s, 1);
        s += __shfl_xor(s, 2);

        // lane with lane4==0 holds row elements 0..3: d.x=d[0], d.y=d[1]
        float loss_c = d.x + s - h0;                 // doctor == control
        float loss_p = d.y + s - h1;                 // doctor == parkinson
        float loss_u = (re == 0) ? h1 : h0;          // doctor == unknown
        float loss   = (doc == 0) ? loss_c : ((doc == 1) ? loss_p : loss_u);
        acc += (lane4 == 0) ? loss : 0.0f;
    }

    // wave (64-lane) reduction
    #pragma unroll
    for (int m = 32; m >= 1; m >>= 1)
        acc += __shfl_xor(acc, m);

    __shared__ float wsum[THREADS / 64];
    const int wid = threadIdx.x >> 6;
    if ((threadIdx.x & 63) == 0) wsum[wid] = acc;
    __syncthreads();

    if (threadIdx.x == 0) {
        float t = 0.0f;
        #pragma unroll
        for (int w = 0; w < THREADS / 64; ++w) t += wsum[w];
        partials[blockIdx.x] = t * invB;             // pre-scaled, ~1e-3 each
    }
}

__global__ __launch_bounds__(THREADS) void mlloss_final(
    const float* __restrict__ partials, float* __restrict__ out, int n)
{
    float acc = 0.0f;
    for (int i = threadIdx.x; i < n; i += THREADS)
        acc += partials[i];

    #pragma unroll
    for (int m = 32; m >= 1; m >>= 1)
        acc += __shfl_xor(acc, m);

    __shared__ float wsum[THREADS / 64];
    const int wid = threadIdx.x >> 6;
    if ((threadIdx.x & 63) == 0) wsum[wid] = acc;
    __syncthreads();

    if (threadIdx.x == 0) {
        float t = 0.0f;
        #pragma unroll
        for (int w = 0; w < THREADS / 64; ++w) t += wsum[w];
        out[0] = t;
    }
}

extern "C" void kernel_launch(void* const* d_in, const int* in_sizes, int n_in,
                              void* d_out, int out_size, void* d_ws, size_t ws_size,
                              hipStream_t stream) {
    const vfloat4* dist4  = (const vfloat4*)d_in[0];
    const int*     doctor = (const int*)d_in[1];
    const int*     real_l = (const int*)d_in[2];
    float*         out    = (float*)d_out;
    float*         part   = (float*)d_ws;  // 4096 floats = 16 KB scratch

    const int B = in_sizes[1];             // doctor_labels element count

    mlloss_partial<<<BLOCKS, THREADS, 0, stream>>>(
        dist4, doctor, real_l, part, B, 1.0f / (float)B);
    mlloss_final<<<1, THREADS, 0, stream>>>(part, out, BLOCKS);
}